// Round 1
// baseline (206.019 us; speedup 1.0000x reference)
//
#include <hip/hip_runtime.h>

// GIoU loss, 3D boxes, matched pairs, sum-reduced and negated.
// Layout per box row: [x1, y1, x2, y2, z1, z2] (6 f32).
// Memory-bound: 192 MB read -> ~30 us floor at 6.3 TB/s achievable.

namespace {

constexpr float kEps = 1e-7f;
constexpr int kThreads = 256;           // multiple of wave=64
constexpr int kBlocks  = 2048;          // ~8 blocks/CU on 256 CUs, grid-stride

__device__ __forceinline__ float giou1(
    float px1, float py1, float px2, float py2, float pz1, float pz2,
    float tx1, float ty1, float tx2, float ty2, float tz1, float tz2)
{
    float vol1 = (px2 - px1) * (py2 - py1) * (pz2 - pz1);
    float vol2 = (tx2 - tx1) * (ty2 - ty1) * (tz2 - tz1);

    float ix = fmaxf(fminf(px2, tx2) - fmaxf(px1, tx1), 0.0f);
    float iy = fmaxf(fminf(py2, ty2) - fmaxf(py1, ty1), 0.0f);
    float iz = fmaxf(fminf(pz2, tz2) - fmaxf(pz1, tz1), 0.0f);
    float inter = ix * iy * iz;
    float uni = vol1 + vol2 - inter;
    float iou = inter / uni;

    float ex = fmaxf(fmaxf(px2, tx2) - fminf(px1, tx1), 0.0f);
    float ey = fmaxf(fmaxf(py2, ty2) - fminf(py1, ty1), 0.0f);
    float ez = fmaxf(fmaxf(pz2, tz2) - fminf(pz1, tz1), 0.0f);
    float enc = ex * ey * ez + kEps;

    return iou - (enc - uni) / enc;
}

// Each thread processes 2 boxes per iteration: 48 B = 3 x float4, fully
// 16B-aligned (48*i is 16-aligned). A wave's 3 dwordx4 loads cover 3 KiB
// contiguous per array -> full cacheline utilization, zero over-fetch.
__global__ __launch_bounds__(kThreads) void giou_partial_kernel(
    const float* __restrict__ pred, const float* __restrict__ targ,
    double* __restrict__ partials, int npairs, int nboxes)
{
    const float4* __restrict__ p4 = reinterpret_cast<const float4*>(pred);
    const float4* __restrict__ t4 = reinterpret_cast<const float4*>(targ);

    double acc = 0.0;
    const int stride = gridDim.x * blockDim.x;
    for (int i = blockIdx.x * blockDim.x + threadIdx.x; i < npairs; i += stride) {
        float4 pa = p4[3 * i + 0];
        float4 pb = p4[3 * i + 1];
        float4 pc = p4[3 * i + 2];
        float4 ta = t4[3 * i + 0];
        float4 tb = t4[3 * i + 1];
        float4 tc = t4[3 * i + 2];

        // box 2i  : x1=pa.x y1=pa.y x2=pa.z y2=pa.w z1=pb.x z2=pb.y
        // box 2i+1: x1=pb.z y1=pb.w x2=pc.x y2=pc.y z1=pc.z z2=pc.w
        float g0 = giou1(pa.x, pa.y, pa.z, pa.w, pb.x, pb.y,
                         ta.x, ta.y, ta.z, ta.w, tb.x, tb.y);
        float g1 = giou1(pb.z, pb.w, pc.x, pc.y, pc.z, pc.w,
                         tb.z, tb.w, tc.x, tc.y, tc.z, tc.w);
        acc += (double)g0 + (double)g1;
    }

    // Defensive odd-N tail (N=4e6 is even, so normally dead code).
    if ((nboxes & 1) && blockIdx.x == 0 && threadIdx.x == 0) {
        const float* pp = pred + (size_t)(nboxes - 1) * 6;
        const float* tt = targ + (size_t)(nboxes - 1) * 6;
        acc += (double)giou1(pp[0], pp[1], pp[2], pp[3], pp[4], pp[5],
                             tt[0], tt[1], tt[2], tt[3], tt[4], tt[5]);
    }

    // Wave (64-lane) reduce, then cross-wave via LDS.
    #pragma unroll
    for (int off = 32; off > 0; off >>= 1)
        acc += __shfl_down(acc, off, 64);

    __shared__ double smem[kThreads / 64];
    const int lane = threadIdx.x & 63;
    const int wid  = threadIdx.x >> 6;
    if (lane == 0) smem[wid] = acc;
    __syncthreads();
    if (threadIdx.x == 0) {
        double s = 0.0;
        #pragma unroll
        for (int w = 0; w < kThreads / 64; ++w) s += smem[w];
        partials[blockIdx.x] = s;  // unconditional: every block writes its slot
    }
}

__global__ __launch_bounds__(kThreads) void giou_final_kernel(
    const double* __restrict__ partials, float* __restrict__ out, int n)
{
    double acc = 0.0;
    for (int i = threadIdx.x; i < n; i += kThreads) acc += partials[i];

    #pragma unroll
    for (int off = 32; off > 0; off >>= 1)
        acc += __shfl_down(acc, off, 64);

    __shared__ double smem[kThreads / 64];
    const int lane = threadIdx.x & 63;
    const int wid  = threadIdx.x >> 6;
    if (lane == 0) smem[wid] = acc;
    __syncthreads();
    if (threadIdx.x == 0) {
        double s = 0.0;
        #pragma unroll
        for (int w = 0; w < kThreads / 64; ++w) s += smem[w];
        out[0] = (float)(-1.0 * s);   // LOSS_WEIGHT * -1 * sum
    }
}

}  // namespace

extern "C" void kernel_launch(void* const* d_in, const int* in_sizes, int n_in,
                              void* d_out, int out_size, void* d_ws, size_t ws_size,
                              hipStream_t stream) {
    const float* pred = (const float*)d_in[0];
    const float* targ = (const float*)d_in[1];
    float* out = (float*)d_out;

    const int nboxes = in_sizes[0] / 6;    // 4,000,000
    const int npairs = nboxes / 2;         // 2,000,000

    double* partials = (double*)d_ws;      // kBlocks * 8 B = 16 KiB << ws_size

    giou_partial_kernel<<<kBlocks, kThreads, 0, stream>>>(
        pred, targ, partials, npairs, nboxes);
    giou_final_kernel<<<1, kThreads, 0, stream>>>(partials, out, kBlocks);
}